// Round 9
// baseline (347.470 us; speedup 1.0000x reference)
//
#include <hip/hip_runtime.h>
#include <math.h>

#define TT 1024
#define HID 7168
#define QL 1536
#define NH 64
#define DD 128
#define NQ 8192
#define TOPK 512
#define NEGF (-1.0e30f)

typedef float  f32x4 __attribute__((ext_vector_type(4)));
typedef short  s16x8 __attribute__((ext_vector_type(8)));
typedef short  s16x4 __attribute__((ext_vector_type(4)));

// ---- workspace byte offsets ----
#define OFF_QB    ((size_t)0)            // ushort q_bf16 [1024][8192] (frag-permuted d)
#define OFF_WQBT  ((size_t)16777216)     // ushort wq_b^T bf16 [8192][1536] (frag-permuted k)
#define OFF_QRB   ((size_t)41943040)     // ushort qr bf16 [1024][1536]     (frag-permuted k)
#define OFF_KPART ((size_t)45088768)     // float kpart [8][1024][192]
#define OFF_KKB   ((size_t)51380224)     // ushort k bf16 [1024][128] (frag-permuted d)
#define OFF_WC    ((size_t)51642368)     // float wc [1024][64]
#define OFF_TRIG  ((size_t)51904512)     // float2 trig [1024][32]
#define OFF_HB    ((size_t)52166656)     // ushort hidden bf16 [1024][7168] (linear)
#define OFF_WKPT  ((size_t)66846720)     // ushort [wk|wp]^T bf16 [192][7168] (linear)

__device__ __forceinline__ unsigned short f2bf(float x) {
  unsigned int u = __builtin_bit_cast(unsigned int, x);
  u = (u + 0x7FFFu + ((u >> 16) & 1u)) >> 16;
  return (unsigned short)u;
}

__device__ __forceinline__ s16x8 ld_frag(const unsigned short* p) {
  s16x4 lo = *(const s16x4*)p;
  s16x4 hi = *(const s16x4*)(p + 16);
  s16x8 r = { lo[0], lo[1], lo[2], lo[3], hi[0], hi[1], hi[2], hi[3] };
  return r;
}

__device__ __forceinline__ void cp16(unsigned short* dst, const unsigned short* src) {
  s16x8 v = *(const s16x8*)src;
  s16x4 lo = { v[0], v[1], v[2], v[3] };
  s16x4 hi = { v[4], v[5], v[6], v[7] };
  *(s16x4*)dst = lo;
  *(s16x4*)(dst + 4) = hi;
}

// frag-permutation: logical 4-group g (k/4) -> physical 4-group within row.
__device__ __forceinline__ int perm4(int g) {
  int k64 = g >> 4, r = g & 15;
  int kk = r >> 3, pc = (r >> 2) & 1, lg = r & 3;
  return k64*16 + kk*8 + lg*2 + pc;
}

// key = (~ascmap(val) << 32) | idx  -> ascending u64 sort == desc val, asc idx
__device__ __forceinline__ unsigned long long packkey(float v, int idx) {
  unsigned int u = __builtin_bit_cast(unsigned int, v);
  unsigned int m = (u & 0x80000000u) ? ~u : (u | 0x80000000u);
  return ((unsigned long long)(~m) << 32) | (unsigned int)idx;
}
__device__ __forceinline__ float unpackval(unsigned long long k) {
  unsigned int m = ~(unsigned int)(k >> 32);
  unsigned int u = (m & 0x80000000u) ? (m ^ 0x80000000u) : ~m;
  return __builtin_bit_cast(float, u);
}

__device__ __forceinline__ unsigned long long shfl_xor_u64(unsigned long long v, int m) {
  unsigned int lo = (unsigned int)v, hi = (unsigned int)(v >> 32);
  lo = __shfl_xor(lo, m); hi = __shfl_xor(hi, m);
  return ((unsigned long long)hi << 32) | lo;
}

__device__ __forceinline__ void cswap_shfl(unsigned long long &v, int j, bool up, int lane) {
  unsigned long long o = shfl_xor_u64(v, j);
  bool keepmin = (((lane & j) == 0) == up);
  unsigned long long mn = v < o ? v : o;
  unsigned long long mx = v < o ? o : v;
  v = keepmin ? mn : mx;
}

#define CSWAP_INTRA(rl, rh, up) { \
  unsigned long long a_ = (rl), b_ = (rh); \
  bool mn_ = a_ < b_; \
  (rl) = (up) ? (mn_ ? a_ : b_) : (mn_ ? b_ : a_); \
  (rh) = (up) ? (mn_ ? b_ : a_) : (mn_ ? a_ : b_); }

// ---------------- trig table ----------------
__global__ void k_trig(const int* __restrict__ pos, float2* __restrict__ trig) {
  int t = blockIdx.x, i = threadIdx.x;
  double inv = pow(10000.0, -(double)i / 32.0);
  double ang = (double)pos[t] * inv;
  trig[t*32 + i] = make_float2((float)cos(ang), (float)sin(ang));
}

// ---------------- fp32 -> bf16 linear (hidden) ----------------
__global__ void k_cvt(const float* __restrict__ in, unsigned short* __restrict__ out) {
  int i = (blockIdx.x*256 + threadIdx.x)*4;
  float4 v = *(const float4*)(in + i);
  s16x4 o = { (short)f2bf(v.x), (short)f2bf(v.y), (short)f2bf(v.z), (short)f2bf(v.w) };
  *(s16x4*)(out + i) = o;
}

// ---------------- qr fp32 -> bf16, frag-permuted k ----------------
__global__ void k_cvtp(const float* __restrict__ in, unsigned short* __restrict__ out) {
  int idx = blockIdx.x*256 + threadIdx.x;
  int row = idx / (QL/4);
  int g   = idx - row*(QL/4);
  float4 v = *(const float4*)(in + (size_t)idx*4);
  s16x4 o = { (short)f2bf(v.x), (short)f2bf(v.y), (short)f2bf(v.z), (short)f2bf(v.w) };
  *(s16x4*)(out + (size_t)row*QL + perm4(g)*4) = o;
}

// ---------------- wq_b -> transposed bf16, frag-permuted k ----------------
__global__ __launch_bounds__(256) void k_trcvt(const float* __restrict__ in,
                                               unsigned short* __restrict__ outT) {
  __shared__ float tileS[64][65];
  int n0 = blockIdx.x*64, k0 = blockIdx.y*64;
  int tid = threadIdx.x;
  for (int c = tid; c < 1024; c += 256) {
    int r = c >> 4, c4 = (c & 15)*4;
    float4 v = *(const float4*)(in + (size_t)(k0+r)*NQ + n0 + c4);
    tileS[r][c4] = v.x; tileS[r][c4+1] = v.y; tileS[r][c4+2] = v.z; tileS[r][c4+3] = v.w;
  }
  __syncthreads();
  for (int c = tid; c < 512; c += 256) {
    int rn = c >> 3, c8 = (c & 7)*8;
    s16x4 a, b;
    #pragma unroll
    for (int u = 0; u < 4; ++u) a[u] = (short)f2bf(tileS[c8+u][rn]);
    #pragma unroll
    for (int u = 0; u < 4; ++u) b[u] = (short)f2bf(tileS[c8+4+u][rn]);
    int gA = (k0 + c8) >> 2;
    *(s16x4*)(outT + (size_t)(n0+rn)*QL + perm4(gA)*4)   = a;
    *(s16x4*)(outT + (size_t)(n0+rn)*QL + perm4(gA+1)*4) = b;
  }
}

// ---------------- wk + wp -> [192][7168] bf16 linear ----------------
__global__ __launch_bounds__(256) void k_trkw(const float* __restrict__ wk,
                                              const float* __restrict__ wp,
                                              unsigned short* __restrict__ wkpT) {
  __shared__ float tileS[64][65];
  int bx = blockIdx.x;
  int k0 = blockIdx.y*64;
  int tid = threadIdx.x;
  const float* src; int stride, c0;
  if (bx < 2) { src = wk; stride = DD; c0 = bx*64; }
  else        { src = wp; stride = NH; c0 = 0; }
  for (int c = tid; c < 1024; c += 256) {
    int r = c >> 4, c4 = (c & 15)*4;
    float4 v = *(const float4*)(src + (size_t)(k0+r)*stride + c0 + c4);
    tileS[r][c4] = v.x; tileS[r][c4+1] = v.y; tileS[r][c4+2] = v.z; tileS[r][c4+3] = v.w;
  }
  __syncthreads();
  int rowOff = bx*64;
  for (int c = tid; c < 512; c += 256) {
    int rn = c >> 3, c8 = (c & 7)*8;
    s16x8 v;
    #pragma unroll
    for (int u = 0; u < 8; ++u) v[u] = (short)f2bf(tileS[c8+u][rn]);
    *(s16x8*)(wkpT + (size_t)(rowOff+rn)*HID + k0 + c8) = v;
  }
}

// ---------------- q = qr @ wq_b : MFMA GEMM, gload_lds + swizzled frag layout ----------------
// epilogue stores qb frag-permuted within each 32-d block (consumer: k_scores)
__global__ __launch_bounds__(256) void k_gemm_q(const unsigned short* __restrict__ qrb,
                                                const unsigned short* __restrict__ wqbt,
                                                const float2* __restrict__ trig,
                                                unsigned short* __restrict__ qb) {
  __shared__ __align__(16) unsigned short As[128*64];
  __shared__ __align__(16) unsigned short Bs[128*64];
  int tid = threadIdx.x;
  int w = tid >> 6, wr = w >> 1, wc = w & 1, l = tid & 63, lg = l >> 4, lm = l & 15;
  int m0 = blockIdx.y*128, n0 = blockIdx.x*128;
  f32x4 acc[4][4] = {};
  for (int k0 = 0; k0 < QL; k0 += 64) {
    __syncthreads();
    #pragma unroll
    for (int u = 0; u < 4; ++u) {
      int c = tid + 256*u;
      int row = c >> 3, cp = c & 7;
      int srcc = (cp ^ (row & 7)) * 8;
      __builtin_amdgcn_global_load_lds(
        (const __attribute__((address_space(1))) unsigned int*)(qrb + (size_t)(m0+row)*QL + k0 + srcc),
        (__attribute__((address_space(3))) unsigned int*)(As + (size_t)c*8), 16, 0, 0);
    }
    #pragma unroll
    for (int u = 0; u < 4; ++u) {
      int c = tid + 256*u;
      int row = c >> 3, cp = c & 7;
      int srcc = (cp ^ (row & 7)) * 8;
      __builtin_amdgcn_global_load_lds(
        (const __attribute__((address_space(1))) unsigned int*)(wqbt + (size_t)(n0+row)*QL + k0 + srcc),
        (__attribute__((address_space(3))) unsigned int*)(Bs + (size_t)c*8), 16, 0, 0);
    }
    __syncthreads();
    #pragma unroll
    for (int kk = 0; kk < 2; ++kk) {
      s16x8 af[4], bfr[4];
      #pragma unroll
      for (int i = 0; i < 4; ++i) {
        int row = wr*64 + i*16 + lm;
        int ch = (kk*4 + lg) ^ (row & 7);
        af[i] = *(const s16x8*)(As + row*64 + ch*8);
      }
      #pragma unroll
      for (int j = 0; j < 4; ++j) {
        int row = wc*64 + j*16 + lm;
        int ch = (kk*4 + lg) ^ (row & 7);
        bfr[j] = *(const s16x8*)(Bs + row*64 + ch*8);
      }
      #pragma unroll
      for (int i = 0; i < 4; ++i)
        #pragma unroll
        for (int j = 0; j < 4; ++j)
          acc[i][j] = __builtin_amdgcn_mfma_f32_16x16x32_bf16(af[i], bfr[j], acc[i][j], 0, 0, 0);
    }
  }
  #pragma unroll
  for (int i = 0; i < 4; ++i) {
    int trow = m0 + wr*64 + i*16 + lg*4;
    if (wc == 0) {
      #pragma unroll
      for (int r = 0; r < 4; ++r) {
        int t = trow + r;
        #pragma unroll
        for (int jj = 0; jj < 2; ++jj) {
          int idx = jj*16 + lm;
          float2 cs = trig[t*32 + idx];
          float x1 = acc[i][jj][r], x2 = acc[i][jj+2][r];
          acc[i][jj][r]   = x1*cs.x - x2*cs.y;
          acc[i][jj+2][r] = x2*cs.x + x1*cs.y;
        }
      }
    }
    #pragma unroll
    for (int j = 0; j < 4; ++j)
      #pragma unroll
      for (int r = 0; r < 4; ++r) {
        int dlin = wc*64 + j*16 + lm;            // within-head d (n-tile 128 == one head)
        int r32 = dlin & 31;
        int dphys = (dlin & ~31) + ((r32 & 15) >> 2)*8 + (r32 >> 4)*4 + (r32 & 3);
        qb[(size_t)(trow + r)*NQ + n0 + dphys] = f2bf(acc[i][j][r]);
      }
  }
}

// ---------------- fused k + w_proj GEMM via bf16 MFMA, split-K 8 ----------------
__global__ __launch_bounds__(256) void k_kw_mfma(const unsigned short* __restrict__ hb,
                                                 const unsigned short* __restrict__ wkpT,
                                                 float* __restrict__ kpart) {
  __shared__ unsigned short As[32*68];
  __shared__ unsigned short Bs[192*68];
  int tid = threadIdx.x;
  int w = tid >> 6, l = tid & 63, lg = l >> 4, lm = l & 15;
  int ks = blockIdx.x, m0 = blockIdx.y*32;
  int kbase = ks*896;
  f32x4 acc[2][3] = {};
  for (int k0 = 0; k0 < 896; k0 += 64) {
    __syncthreads();
    for (int c = tid; c < 1792; c += 256) {
      int row = c >> 3, col8 = (c & 7)*8;
      if (row < 32)
        cp16(&As[row*68 + col8], hb + (size_t)(m0+row)*HID + kbase + k0 + col8);
      else
        cp16(&Bs[(row-32)*68 + col8], wkpT + (size_t)(row-32)*HID + kbase + k0 + col8);
    }
    __syncthreads();
    #pragma unroll
    for (int kk = 0; kk < 2; ++kk) {
      int kb = kk*32 + 4*lg;
      s16x8 af[2], bfr[3];
      #pragma unroll
      for (int i = 0; i < 2; ++i) af[i] = ld_frag(&As[(i*16 + lm)*68 + kb]);
      #pragma unroll
      for (int j = 0; j < 3; ++j) bfr[j] = ld_frag(&Bs[(w*48 + j*16 + lm)*68 + kb]);
      #pragma unroll
      for (int i = 0; i < 2; ++i)
        #pragma unroll
        for (int j = 0; j < 3; ++j)
          acc[i][j] = __builtin_amdgcn_mfma_f32_16x16x32_bf16(af[i], bfr[j], acc[i][j], 0, 0, 0);
    }
  }
  #pragma unroll
  for (int i = 0; i < 2; ++i)
    #pragma unroll
    for (int j = 0; j < 3; ++j)
      #pragma unroll
      for (int r = 0; r < 4; ++r) {
        int row = m0 + i*16 + lg*4 + r, col = w*48 + j*16 + lm;
        kpart[(size_t)ks*TT*192 + (size_t)row*192 + col] = acc[i][j][r];
      }
}

// ---------------- wc[t,h] ----------------
__global__ void k_post_w(const float* __restrict__ kpart,
                         const float* __restrict__ bp,
                         float* __restrict__ wcq) {
  int g = blockIdx.x*256 + threadIdx.x;
  int t = g >> 6, h = g & 63;
  float s = 0.f;
  for (int ks = 0; ks < 8; ++ks)
    s += kpart[(size_t)ks*TT*192 + (size_t)t*192 + 128 + h];
  s = (s + bp[h]) * 0.08838834764831845f;
  wcq[t*64 + h] = s * 0.125f;
}

// ---------------- k partials -> LN -> RoPE -> bf16 (frag-permuted d) ----------------
__global__ __launch_bounds__(128) void k_post_k(const float* __restrict__ kpart,
                                                const float* __restrict__ kg,
                                                const float* __restrict__ kb,
                                                const float2* __restrict__ trig,
                                                unsigned short* __restrict__ kkb) {
  __shared__ float red[128];
  __shared__ float row[128];
  int t = blockIdx.x, d = threadIdx.x;
  float v = 0.f;
  for (int ks = 0; ks < 8; ++ks)
    v += kpart[(size_t)ks*TT*192 + (size_t)t*192 + d];
  red[d] = v; __syncthreads();
  for (int off = 64; off; off >>= 1) { if (d < off) red[d] += red[d+off]; __syncthreads(); }
  float mu = red[0] * (1.f/128.f); __syncthreads();
  float diff = v - mu;
  red[d] = diff*diff; __syncthreads();
  for (int off = 64; off; off >>= 1) { if (d < off) red[d] += red[d+off]; __syncthreads(); }
  float var = red[0] * (1.f/128.f);
  float rsq = 1.f / sqrtf(var + 1e-6f);
  float kn = (v - mu) * rsq * kg[d] + kb[d];
  row[d] = kn; __syncthreads();
  float outv;
  if (d < 32) {
    float2 cs = trig[t*32 + d];
    outv = row[d]*cs.x - row[d+32]*cs.y;
  } else if (d < 64) {
    float2 cs = trig[t*32 + d - 32];
    outv = row[d]*cs.x + row[d-32]*cs.y;
  } else outv = kn;
  int r = d & 31;
  int phys = (d & ~31) + ((r & 15) >> 2)*8 + (r >> 4)*4 + (r & 3);
  kkb[(size_t)t*DD + phys] = f2bf(outv);
}

// ---------------- scores: one wave per t-row, barrier-free register bitonic top-512 ----------------
__global__ __launch_bounds__(64) void k_scores(const unsigned short* __restrict__ qb,
                                               const unsigned short* __restrict__ kkb,
                                               const float* __restrict__ wcq,
                                               const int* __restrict__ pos,
                                               float* __restrict__ out) {
  __shared__ unsigned long long keys[1024];   // 8 KB, wave-local
  int lane = threadIdx.x;
  int bid = blockIdx.x;
  int t = (bid & 1) ? (1023 - (bid >> 1)) : (bid >> 1);   // heavy/light interleave
  int lg = lane >> 4, lm = lane & 15;

  // Q fragments in registers (frag-permuted qb: one 16B load each)
  s16x8 qf[4][4];
  #pragma unroll
  for (int j = 0; j < 4; ++j)
    #pragma unroll
    for (int ksb = 0; ksb < 4; ++ksb)
      qf[j][ksb] = *(const s16x8*)(qb + (size_t)t*NQ + (j*16 + lm)*DD + ksb*32 + lg*8);
  float wreg[4];
  #pragma unroll
  for (int j = 0; j < 4; ++j) wreg[j] = wcq[t*64 + j*16 + lm];
  int post = pos[t];

  int nst = (t >> 4) + 1;           // 16-row s-subtiles covering s <= t
  for (int st = 0; st < nst; ++st) {
    int s0 = st << 4;
    const unsigned short* kb0 = kkb + (size_t)(s0 + lm)*DD + lg*8;
    f32x4 acc[4] = {};
    #pragma unroll
    for (int ksb = 0; ksb < 4; ++ksb) {
      s16x8 af = *(const s16x8*)(kb0 + ksb*32);
      #pragma unroll
      for (int j = 0; j < 4; ++j)
        acc[j] = __builtin_amdgcn_mfma_f32_16x16x32_bf16(af, qf[j][ksb], acc[j], 0, 0, 0);
    }
    #pragma unroll
    for (int r = 0; r < 4; ++r) {
      float p = 0.f;
      #pragma unroll
      for (int j = 0; j < 4; ++j) p += fmaxf(acc[j][r], 0.f) * wreg[j];
      p += __shfl_xor(p, 1); p += __shfl_xor(p, 2);
      p += __shfl_xor(p, 4); p += __shfl_xor(p, 8);
      if (lm == 0) {
        int s = s0 + lg*4 + r;
        keys[s] = packkey((post >= pos[s]) ? p : NEGF, s);
      }
    }
  }
  __syncthreads();   // single wave: cheap lgkmcnt drain + barrier

  int filled = nst << 4;
  unsigned long long r0,r1,r2,r3,r4,r5,r6,r7,r8,r9,r10,r11,r12,r13,r14,r15;
  {
    unsigned long long rr[16];
    #pragma unroll
    for (int i = 0; i < 16; ++i) {
      int e = i*64 + lane;
      rr[i] = (e < filled) ? keys[e] : packkey(NEGF, e);
    }
    r0=rr[0]; r1=rr[1]; r2=rr[2]; r3=rr[3]; r4=rr[4]; r5=rr[5]; r6=rr[6]; r7=rr[7];
    r8=rr[8]; r9=rr[9]; r10=rr[10]; r11=rr[11]; r12=rr[12]; r13=rr[13]; r14=rr[14]; r15=rr[15];
  }
  #define ALLREG(OP) { OP(r0,0) OP(r1,1) OP(r2,2) OP(r3,3) OP(r4,4) OP(r5,5) OP(r6,6) OP(r7,7) \
                       OP(r8,8) OP(r9,9) OP(r10,10) OP(r11,11) OP(r12,12) OP(r13,13) OP(r14,14) OP(r15,15) }
  // stages kk=2..32: up depends on lane only
  for (int kk = 2; kk <= 32; kk <<= 1) {
    for (int j = kk >> 1; j >= 1; j >>= 1) {
      bool up = true; // placeholder
      #define SOP(R,I) cswap_shfl(R, j, (lane & kk) == 0, lane);
      ALLREG(SOP)
      #undef SOP
      (void)up;
    }
  }
  // kk=64: up = ((i&1)==0)
  for (int j = 32; j >= 1; j >>= 1) {
    #define SOP(R,I) cswap_shfl(R, j, ((I) & 1) == 0, lane);
    ALLREG(SOP)
    #undef SOP
  }
  // kk=128: intra j=64, then shfl; up = ((i&2)==0)
  CSWAP_INTRA(r0,r1,true)  CSWAP_INTRA(r2,r3,false) CSWAP_INTRA(r4,r5,true)  CSWAP_INTRA(r6,r7,false)
  CSWAP_INTRA(r8,r9,true)  CSWAP_INTRA(r10,r11,false) CSWAP_INTRA(r12,r13,true) CSWAP_INTRA(r14,r15,false)
  for (int j = 32; j >= 1; j >>= 1) {
    #define SOP(R,I) cswap_shfl(R, j, ((I) & 2) == 0, lane);
    ALLREG(SOP)
    #undef SOP
  }
  // kk=256: up = ((i&4)==0); intra j=128 (i,i+2), j=64 (i,i+1), then shfl
  CSWAP_INTRA(r0,r2,true)  CSWAP_INTRA(r1,r3,true)  CSWAP_INTRA(r4,r6,false)  CSWAP_INTRA(r5,r7,false)
  CSWAP_INTRA(r8,r10,true) CSWAP_INTRA(r9,r11,true) CSWAP_INTRA(r12,r14,false) CSWAP_INTRA(r13,r15,false)
  CSWAP_INTRA(r0,r1,true)  CSWAP_INTRA(r2,r3,true)  CSWAP_INTRA(r4,r5,false)  CSWAP_INTRA(r6,r7,false)
  CSWAP_INTRA(r8,r9,true)  CSWAP_INTRA(r10,r11,true) CSWAP_INTRA(r12,r13,false) CSWAP_INTRA(r14,r15,false)
  for (int j = 32; j >= 1; j >>= 1) {
    #define SOP(R,I) cswap_shfl(R, j, ((I) & 4) == 0, lane);
    ALLREG(SOP)
    #undef SOP
  }
  // kk=512: up = ((i&8)==0); intra j=256 (i,i+4), 128 (i,i+2), 64 (i,i+1), then shfl
  CSWAP_INTRA(r0,r4,true)  CSWAP_INTRA(r1,r5,true)  CSWAP_INTRA(r2,r6,true)  CSWAP_INTRA(r3,r7,true)
  CSWAP_INTRA(r8,r12,false) CSWAP_INTRA(r9,r13,false) CSWAP_INTRA(r10,r14,false) CSWAP_INTRA(r11,r15,false)
  CSWAP_INTRA(r0,r2,true)  CSWAP_INTRA(r1,r3,true)  CSWAP_INTRA(r4,r6,true)  CSWAP_INTRA(r5,r7,true)
  CSWAP_INTRA(r8,r10,false) CSWAP_INTRA(r9,r11,false) CSWAP_INTRA(r12,r14,false) CSWAP_INTRA(r13,r15,false)
  CSWAP_INTRA(r0,r1,true)  CSWAP_INTRA(r2,r3,true)  CSWAP_INTRA(r4,r5,true)  CSWAP_INTRA(r6,r7,true)
  CSWAP_INTRA(r8,r9,false) CSWAP_INTRA(r10,r11,false) CSWAP_INTRA(r12,r13,false) CSWAP_INTRA(r14,r15,false)
  for (int j = 32; j >= 1; j >>= 1) {
    #define SOP(R,I) cswap_shfl(R, j, ((I) & 8) == 0, lane);
    ALLREG(SOP)
    #undef SOP
  }
  // kk=1024 (ascending): j=512 split keeps mins in i<8; then merge lower half only
  CSWAP_INTRA(r0,r8,true) CSWAP_INTRA(r1,r9,true) CSWAP_INTRA(r2,r10,true) CSWAP_INTRA(r3,r11,true)
  CSWAP_INTRA(r4,r12,true) CSWAP_INTRA(r5,r13,true) CSWAP_INTRA(r6,r14,true) CSWAP_INTRA(r7,r15,true)
  CSWAP_INTRA(r0,r4,true) CSWAP_INTRA(r1,r5,true) CSWAP_INTRA(r2,r6,true) CSWAP_INTRA(r3,r7,true)
  CSWAP_INTRA(r0,r2,true) CSWAP_INTRA(r1,r3,true) CSWAP_INTRA(r4,r6,true) CSWAP_INTRA(r5,r7,true)
  CSWAP_INTRA(r0,r1,true) CSWAP_INTRA(r2,r3,true) CSWAP_INTRA(r4,r5,true) CSWAP_INTRA(r6,r7,true)
  for (int j = 32; j >= 1; j >>= 1) {
    cswap_shfl(r0, j, true, lane); cswap_shfl(r1, j, true, lane);
    cswap_shfl(r2, j, true, lane); cswap_shfl(r3, j, true, lane);
    cswap_shfl(r4, j, true, lane); cswap_shfl(r5, j, true, lane);
    cswap_shfl(r6, j, true, lane); cswap_shfl(r7, j, true, lane);
  }
  // output positions p = i*64 + lane for i<8
  {
    unsigned long long rl[8] = {r0,r1,r2,r3,r4,r5,r6,r7};
    #pragma unroll
    for (int i = 0; i < 8; ++i) {
      int p = i*64 + lane;
      float v = unpackval(rl[i]);
      out[(size_t)t*TOPK + p] = v;
      out[(size_t)TT*TOPK + (size_t)t*TOPK + p] =
          (v > 0.5f*NEGF) ? (float)(unsigned int)(rl[i] & 0xFFFFFFFFu) : -1.0f;
    }
  }
}

extern "C" void kernel_launch(void* const* d_in, const int* in_sizes, int n_in,
                              void* d_out, int out_size, void* d_ws, size_t ws_size,
                              hipStream_t stream) {
  const float* hidden = (const float*)d_in[0];
  const float* qr     = (const float*)d_in[1];
  const float* wqb    = (const float*)d_in[2];
  const float* wk     = (const float*)d_in[3];
  const float* kg     = (const float*)d_in[4];
  const float* kb     = (const float*)d_in[5];
  const float* wp     = (const float*)d_in[6];
  const float* bp     = (const float*)d_in[7];
  const int*   pos    = (const int*)d_in[8];
  float* out = (float*)d_out;

  char* W = (char*)d_ws;
  unsigned short* qbuf  = (unsigned short*)(W + OFF_QB);
  unsigned short* wqbt  = (unsigned short*)(W + OFF_WQBT);
  unsigned short* qrb   = (unsigned short*)(W + OFF_QRB);
  float*          kpart = (float*)(W + OFF_KPART);
  unsigned short* kkbuf = (unsigned short*)(W + OFF_KKB);
  float*          wcq   = (float*)(W + OFF_WC);
  float2*         trig  = (float2*)(W + OFF_TRIG);
  unsigned short* hb    = (unsigned short*)(W + OFF_HB);
  unsigned short* wkpT  = (unsigned short*)(W + OFF_WKPT);

  k_trig   <<<TT, 32, 0, stream>>>(pos, trig);
  k_cvtp   <<<(TT*QL/4)/256, 256, 0, stream>>>(qr, qrb);
  k_cvt    <<<(TT*HID)/1024, 256, 0, stream>>>(hidden, hb);
  k_trcvt  <<<dim3(NQ/64, QL/64), 256, 0, stream>>>(wqb, wqbt);
  k_trkw   <<<dim3(3, HID/64), 256, 0, stream>>>(wk, wp, wkpT);
  k_gemm_q <<<dim3(NQ/128, TT/128), 256, 0, stream>>>(qrb, wqbt, trig, qbuf);
  k_kw_mfma<<<dim3(8, TT/32), 256, 0, stream>>>(hb, wkpT, kpart);
  k_post_w <<<(TT*NH)/256, 256, 0, stream>>>(kpart, bp, wcq);
  k_post_k <<<TT, 128, 0, stream>>>(kpart, kg, kb, trig, kkbuf);
  k_scores <<<TT, 64, 0, stream>>>(qbuf, kkbuf, wcq, pos, out);
}